// Round 2
// baseline (206.953 us; speedup 1.0000x reference)
//
#include <hip/hip_runtime.h>
#include <math.h>

#define BB 32
#define SS 512
#define HH 256
#define TT 48
#define START_IDX 46
#define STOP_IDX 47

typedef __attribute__((ext_vector_type(8))) short short8;
typedef __attribute__((ext_vector_type(4))) float floatx4;

__device__ __forceinline__ float rfl(float x) {
    return __int_as_float(__builtin_amdgcn_readfirstlane(__float_as_int(x)));
}
__device__ __forceinline__ unsigned int bf16_rne(float x) {
    const unsigned int u = __float_as_uint(x);
    return (u + 0x7fffu + ((u >> 16) & 1u)) >> 16;
}
__device__ __forceinline__ float bf2f(unsigned short h) {
    return __uint_as_float(((unsigned int)h) << 16);
}

// ---------------------------------------------------------------------------
// K1 (prep): blocks 0..3 build w B-frags (2 k-groups each) -> Wbuf;
//            block 4 builds E=exp(trans) B-frags -> Ebuf and zeroes cnt/gold.
// ---------------------------------------------------------------------------
__global__ __launch_bounds__(256) void prep_kernel(
    const float* __restrict__ w, const float* __restrict__ trans,
    uint4* __restrict__ Ebuf, uint4* __restrict__ Wbuf,
    unsigned int* __restrict__ cnt, float* __restrict__ goldb)
{
    __shared__ unsigned short wb[64 * 50];
    const int tid = threadIdx.x, blk = blockIdx.x;

    if (blk == 4) {
        if (tid < 32) { cnt[tid] = 0u; goldb[tid] = 0.f; }
        if (tid < 64) {
            const int g = tid >> 4, cl = tid & 15;
#pragma unroll
            for (int kc = 0; kc < 2; ++kc)
#pragma unroll
                for (int nt = 0; nt < 3; ++nt) {
                    unsigned int p[4];
#pragma unroll
                    for (int h2 = 0; h2 < 4; ++h2) {
                        const int k = kc * 32 + g * 8 + 2 * h2;
                        const int n = nt * 16 + cl;
                        const float lo = (k     < TT) ? __expf(trans[k * TT + n])       : 0.f;
                        const float hi = (k + 1 < TT) ? __expf(trans[(k + 1) * TT + n]) : 0.f;
                        p[h2] = bf16_rne(lo) | (bf16_rne(hi) << 16);
                    }
                    Ebuf[(kc * 3 + nt) * 64 + tid] = make_uint4(p[0], p[1], p[2], p[3]);
                }
        }
        return;
    }

    // w rows [kt0*32, kt0*32+64) -> bf16 LDS -> 6 frag-blocks
    const int kt0 = blk * 2;
    const int R0  = kt0 * 32;
    for (int i = tid; i < 768; i += 256) {
        const float4 v = ((const float4*)w)[R0 * 12 + i];
        const int lr = i / 12, c4 = (i - lr * 12) * 4;
        unsigned short* d = &wb[lr * 50 + c4];
        d[0] = (unsigned short)bf16_rne(v.x);
        d[1] = (unsigned short)bf16_rne(v.y);
        d[2] = (unsigned short)bf16_rne(v.z);
        d[3] = (unsigned short)bf16_rne(v.w);
    }
    __syncthreads();
    for (int idx = tid; idx < 384; idx += 256) {
        const int fbl = idx >> 6, l = idx & 63;
        const int ktl = fbl / 3, nt = fbl - ktl * 3;
        const int kb  = ktl * 32 + (l >> 4) * 8;
        const int col = nt * 16 + (l & 15);
        unsigned int p[4];
#pragma unroll
        for (int h2 = 0; h2 < 4; ++h2) {
            const unsigned int lo = wb[(kb + 2 * h2)     * 50 + col];
            const unsigned int hi = wb[(kb + 2 * h2 + 1) * 50 + col];
            p[h2] = lo | (hi << 16);
        }
        Wbuf[((kt0 + ktl) * 3 + nt) * 64 + l] = make_uint4(p[0], p[1], p[2], p[3]);
    }
}

// ---------------------------------------------------------------------------
// K2 (fused): per (b,chunk) block of 192 threads:
//   phase A: emission of its 16 rows (MFMA, f direct from global, w-frags
//            from ws) -> ebuf(bf16 exp) + plds(f32 pre-exp) + exem global
//   phase B: f32 gold partial for its 16 steps -> atomicAdd(goldb[b])
//   phase C: 16-step chunk scan -> Qs, Ls3       (proven round-1 code)
//   phase D: last block of batch b (device fence + counter) runs the
//            3-wave blocked-scan finalize inline and writes out[b].
// ---------------------------------------------------------------------------
__global__ __launch_bounds__(192, 3) void fused_kernel(
    const float* __restrict__ f, const float* __restrict__ bias,
    const float* __restrict__ trans, const int* __restrict__ lengths,
    const int* __restrict__ tags,
    unsigned short* __restrict__ exem, unsigned short* __restrict__ Qs,
    float* __restrict__ Ls3, const uint4* __restrict__ Ebuf,
    const uint4* __restrict__ Wbuf, unsigned int* __restrict__ cnt,
    float* __restrict__ goldb, float* __restrict__ out)
{
    __shared__ __align__(16) unsigned short ebuf[16 * TT];          // 1536 B
    __shared__ __align__(16) unsigned short abuf[3][17 * 56];       // 5712 B
    __shared__ __align__(16) unsigned short pool_us[3 * 2704];      // 16224 B (plds overlay / P_w tiles)
    __shared__ float Lsl[96], fal[96], Lw[3];
    __shared__ __align__(16) unsigned short vlds[64];
    __shared__ int flag;

    const int bc = blockIdx.x, b = bc >> 5, c = bc & 31;
    const int len = lengths[b];
    const int tid = threadIdx.x, wv = tid >> 6, l = tid & 63, g = l >> 4, cl = l & 15;
    const int base16 = c << 4;

    const int nraw = (len - 1) - base16;
    const bool active = (nraw >= 0);
    int nsteps = (nraw > 16) ? 16 : nraw;

    float* plds = (float*)pool_us;     // [16][48] f32 pre-exp emission

    // ---- phase A: emission (wave wv = column tile nt) ----
    if (active) {
        const float* frow = f + ((size_t)b * SS + base16 + cl) * HH + g * 8;
        float4 fv[8][2];
#pragma unroll
        for (int kt = 0; kt < 8; ++kt) {
            fv[kt][0] = *(const float4*)(frow + kt * 32);
            fv[kt][1] = *(const float4*)(frow + kt * 32 + 4);
        }
        uint4 wf[8];
#pragma unroll
        for (int kt = 0; kt < 8; ++kt) wf[kt] = Wbuf[(kt * 3 + wv) * 64 + l];

        floatx4 acc = {0.f, 0.f, 0.f, 0.f};
#pragma unroll
        for (int kt = 0; kt < 8; ++kt) {
            const unsigned int a0 = bf16_rne(fv[kt][0].x) | (bf16_rne(fv[kt][0].y) << 16);
            const unsigned int a1 = bf16_rne(fv[kt][0].z) | (bf16_rne(fv[kt][0].w) << 16);
            const unsigned int a2 = bf16_rne(fv[kt][1].x) | (bf16_rne(fv[kt][1].y) << 16);
            const unsigned int a3 = bf16_rne(fv[kt][1].z) | (bf16_rne(fv[kt][1].w) << 16);
            const short8 Af = __builtin_bit_cast(short8, make_uint4(a0, a1, a2, a3));
            acc = __builtin_amdgcn_mfma_f32_16x16x32_bf16(
                Af, __builtin_bit_cast(short8, wf[kt]), acc, 0, 0, 0);
        }
        const float bcol = bias[wv * 16 + cl];
#pragma unroll
        for (int r = 0; r < 4; ++r) {
            const int row = 4 * g + r, col = wv * 16 + cl;
            const float el = acc[r] + bcol;              // f32 log-emission
            plds[row * 48 + col] = el;
            ebuf[row * TT + col] = (unsigned short)bf16_rne(__expf(el));
        }
    }
    __syncthreads();

    if (active) {
        // exem write: 16x48 bf16 tile, coalesced 96 x uint4
        if (tid < 96)
            ((uint4*)(exem + ((size_t)b * SS + base16) * TT))[tid] = ((const uint4*)ebuf)[tid];

        // ---- phase B: f32 gold partial (wave 0) ----
        if (wv == 0) {
            float gp = 0.f;
            if (l < 16) {
                const int s = base16 + l;
                if (s < len) {
                    const int tag  = tags[b * SS + s];
                    const int from = (s == 0) ? START_IDX : tags[b * SS + s - 1];
                    gp = plds[l * 48 + tag] + trans[from * TT + tag];
                }
            }
            gp += __shfl_xor(gp, 8); gp += __shfl_xor(gp, 4);
            gp += __shfl_xor(gp, 2); gp += __shfl_xor(gp, 1);
            if (l == 0) atomicAdd(&goldb[b], gp);
        }
    }

    // ---- phase C: chunk scan (wave wv = rowblock), round-1 proven code ----
    if (nsteps > 0) {
        uint4 Bf[2][3];
#pragma unroll
        for (int kc = 0; kc < 2; ++kc)
#pragma unroll
            for (int nt = 0; nt < 3; ++nt)
                Bf[kc][nt] = Ebuf[(kc * 3 + nt) * 64 + l];

        floatx4 acc[3];
#pragma unroll
        for (int nt = 0; nt < 3; ++nt)
#pragma unroll
            for (int r = 0; r < 4; ++r)
                acc[nt][r] = (16 * wv + 4 * g + r == nt * 16 + cl) ? 1.f : 0.f;

        float ev[3];
#pragma unroll
        for (int nt = 0; nt < 3; ++nt) ev[nt] = bf2f(ebuf[nt * 16 + cl]);

        float Lrb = 0.f;
        unsigned short* aw = abuf[wv];

        for (int s = 0; s < nsteps; ++s) {
            float scale = 1.f;
            if (s == 8) {
                const float sig = rfl(acc[0][0]);
                Lrb = __logf(sig);
                scale = __builtin_amdgcn_rcpf(sig);
            }
            const float f0 = ev[0] * scale, f1 = ev[1] * scale, f2 = ev[2] * scale;
#pragma unroll
            for (int r = 0; r < 4; ++r) {
                const int rw = (4 * g + r) * 56;
                aw[rw +      cl] = (unsigned short)bf16_rne(acc[0][r] * f0);
                aw[rw + 16 + cl] = (unsigned short)bf16_rne(acc[1][r] * f1);
                aw[rw + 32 + cl] = (unsigned short)bf16_rne(acc[2][r] * f2);
            }
            if (s + 1 < nsteps) {
#pragma unroll
                for (int nt = 0; nt < 3; ++nt)
                    ev[nt] = bf2f(ebuf[(s + 1) * TT + nt * 16 + cl]);
            }
            uint4 a0 = *(const uint4*)&aw[cl * 56 + g * 8];
            uint4 a1 = *(const uint4*)&aw[cl * 56 + 32 + g * 8];
            if (g >= 2) a1 = make_uint4(0, 0, 0, 0);
            const floatx4 z = {0.f, 0.f, 0.f, 0.f};
#pragma unroll
            for (int nt = 0; nt < 3; ++nt) {
                floatx4 d = __builtin_amdgcn_mfma_f32_16x16x32_bf16(
                    __builtin_bit_cast(short8, a0), __builtin_bit_cast(short8, Bf[0][nt]), z, 0, 0, 0);
                d = __builtin_amdgcn_mfma_f32_16x16x32_bf16(
                    __builtin_bit_cast(short8, a1), __builtin_bit_cast(short8, Bf[1][nt]), d, 0, 0, 0);
                acc[nt] = d;
            }
        }

        unsigned short* qb = Qs + (size_t)bc * (TT * 64);
#pragma unroll
        for (int nt = 0; nt < 3; ++nt) {
            const unsigned int lo = bf16_rne(acc[nt][0]) | (bf16_rne(acc[nt][1]) << 16);
            const unsigned int hi = bf16_rne(acc[nt][2]) | (bf16_rne(acc[nt][3]) << 16);
            *(uint2*)&qb[(nt * 16 + cl) * 64 + 16 * wv + 4 * g] = make_uint2(lo, hi);
        }
        if (l == 0) Ls3[bc * 3 + wv] = Lrb;
    }

    // ---- counter: last block of batch b becomes the finalizer ----
    __threadfence();                 // release our exem/Qs/Ls3 writes
    __syncthreads();
    if (tid == 0) flag = (atomicAdd(&cnt[b], 1u) == 31u) ? 1 : 0;
    __syncthreads();
    if (!flag) return;
    __threadfence();                 // acquire other blocks' writes

    // ---- phase D: finalize (3-wave blocked scan + combine) ----
    const int nc = (len - 1 + 15) >> 4;      // 16..32
    if (tid < 96) Lsl[tid] = (tid < nc * 3) ? Ls3[b * 96 + tid] : 0.f;
    __syncthreads();
    if (tid < 96) fal[tid] = __expf(Lsl[tid] - Lsl[(tid / 3) * 3]);
    __syncthreads();

    unsigned short* paw = pool_us + wv * 2704;   // scan A-tile, then P_w store
    const int K3 = (nc + 2) / 3;
    const int c0 = wv * K3;
    const int c1 = (c0 + K3 < nc) ? c0 + K3 : nc;

    floatx4 M[3][3];
#pragma unroll
    for (int mt = 0; mt < 3; ++mt)
#pragma unroll
        for (int nt = 0; nt < 3; ++nt)
#pragma unroll
            for (int r = 0; r < 4; ++r)
                M[mt][nt][r] = (16 * mt + 4 * g + r == 16 * nt + cl) ? 1.f : 0.f;

    float inv = 1.f, Lacc = 0.f;
    const unsigned short* qbase = Qs + (size_t)(b * 32) * (TT * 64);

    uint4 pB0[3], pB1[3];
#pragma unroll
    for (int nt = 0; nt < 3; ++nt) {
        pB0[nt] = *(const uint4*)&qbase[(size_t)c0 * TT * 64 + (nt * 16 + cl) * 64 + g * 8];
        pB1[nt] = *(const uint4*)&qbase[(size_t)c0 * TT * 64 + (nt * 16 + cl) * 64 + 32 + g * 8];
    }

    for (int c2 = c0; c2 < c1; ++c2) {
        uint4 B0[3], B1[3];
#pragma unroll
        for (int nt = 0; nt < 3; ++nt) {
            B0[nt] = pB0[nt];
            B1[nt] = pB1[nt];
            if (g >= 2) B1[nt] = make_uint4(0, 0, 0, 0);
        }
        const int cn = (c2 + 1 < c1) ? c2 + 1 : c2;
#pragma unroll
        for (int nt = 0; nt < 3; ++nt) {
            pB0[nt] = *(const uint4*)&qbase[(size_t)cn * TT * 64 + (nt * 16 + cl) * 64 + g * 8];
            pB1[nt] = *(const uint4*)&qbase[(size_t)cn * TT * 64 + (nt * 16 + cl) * 64 + 32 + g * 8];
        }

        const float f0 = inv * fal[c2 * 3 + 0];
        const float f1 = inv * fal[c2 * 3 + 1];
        const float f2 = inv * fal[c2 * 3 + 2];
        Lacc += Lsl[c2 * 3];

#pragma unroll
        for (int mt = 0; mt < 3; ++mt)
#pragma unroll
            for (int r = 0; r < 4; ++r) {
                const int rw = (16 * mt + 4 * g + r) * 56;
                paw[rw +      cl] = (unsigned short)bf16_rne(M[mt][0][r] * f0);
                paw[rw + 16 + cl] = (unsigned short)bf16_rne(M[mt][1][r] * f1);
                paw[rw + 32 + cl] = (unsigned short)bf16_rne(M[mt][2][r] * f2);
            }

        uint4 A0[3], A1[3];
#pragma unroll
        for (int mt = 0; mt < 3; ++mt) {
            A0[mt] = *(const uint4*)&paw[(16 * mt + cl) * 56 + g * 8];
            A1[mt] = *(const uint4*)&paw[(16 * mt + cl) * 56 + 32 + g * 8];
            if (g >= 2) A1[mt] = make_uint4(0, 0, 0, 0);
        }

        const floatx4 z = {0.f, 0.f, 0.f, 0.f};
#pragma unroll
        for (int mt = 0; mt < 3; ++mt)
#pragma unroll
            for (int nt = 0; nt < 3; ++nt) {
                floatx4 d = __builtin_amdgcn_mfma_f32_16x16x32_bf16(
                    __builtin_bit_cast(short8, A0[mt]), __builtin_bit_cast(short8, B0[nt]), z, 0, 0, 0);
                d = __builtin_amdgcn_mfma_f32_16x16x32_bf16(
                    __builtin_bit_cast(short8, A1[mt]), __builtin_bit_cast(short8, B1[nt]), d, 0, 0, 0);
                M[mt][nt] = d;
            }
        const float sig = rfl(M[0][0][0]);
        inv = __builtin_amdgcn_rcpf(sig);
        Lacc += __logf(sig);
    }

    // store P_w col-major (stride 56) into paw; scan reads are done
#pragma unroll
    for (int mt = 0; mt < 3; ++mt)
#pragma unroll
        for (int nt = 0; nt < 3; ++nt) {
            const unsigned int lo = bf16_rne(M[mt][nt][0] * inv) | (bf16_rne(M[mt][nt][1] * inv) << 16);
            const unsigned int hi = bf16_rne(M[mt][nt][2] * inv) | (bf16_rne(M[mt][nt][3] * inv) << 16);
            *(uint2*)&paw[(nt * 16 + cl) * 56 + 16 * mt + 4 * g] = make_uint2(lo, hi);
        }
    if (l == 0) Lw[wv] = Lacc;
    __syncthreads();

    // ---- wave 0: v · P_0 · P_1 · P_2, then terminal ----
    if (wv == 0) {
        const float vj = (l < TT) ? __expf(trans[START_IDX * TT + l]) : 0.f;
        vlds[l] = (unsigned short)bf16_rne(vj);

        float L = 0.f, cinv = 1.f;
        floatx4 accn[3];

        for (int w3 = 0; w3 < 3; ++w3) {
            const unsigned short* pw = pool_us + w3 * 2704;
            uint4 B0[3], B1[3];
#pragma unroll
            for (int nt = 0; nt < 3; ++nt) {
                B0[nt] = *(const uint4*)&pw[(nt * 16 + cl) * 56 + g * 8];
                B1[nt] = *(const uint4*)&pw[(nt * 16 + cl) * 56 + 32 + g * 8];
                if (g >= 2) B1[nt] = make_uint4(0, 0, 0, 0);
            }
            const uint4 A0 = *(const uint4*)&vlds[g * 8];
            const uint4 A1 = *(const uint4*)&vlds[32 + g * 8];

            const floatx4 z = {0.f, 0.f, 0.f, 0.f};
#pragma unroll
            for (int nt = 0; nt < 3; ++nt) {
                floatx4 d = __builtin_amdgcn_mfma_f32_16x16x32_bf16(
                    __builtin_bit_cast(short8, A0), __builtin_bit_cast(short8, B0[nt]), z, 0, 0, 0);
                d = __builtin_amdgcn_mfma_f32_16x16x32_bf16(
                    __builtin_bit_cast(short8, A1), __builtin_bit_cast(short8, B1[nt]), d, 0, 0, 0);
                accn[nt] = d;
            }
            const float sig = rfl(accn[0][0]);
            cinv = __builtin_amdgcn_rcpf(sig);
            L += __logf(sig) + Lw[w3];
            if (w3 < 2 && l < 16) {
                vlds[ 0 + l] = (unsigned short)bf16_rne(accn[0][0] * cinv);
                vlds[16 + l] = (unsigned short)bf16_rne(accn[1][0] * cinv);
                vlds[32 + l] = (unsigned short)bf16_rne(accn[2][0] * cinv);
            }
        }

        float term = 0.f;
        if (l < 16) {
            const size_t erow = ((size_t)b * SS + (len - 1)) * TT;
#pragma unroll
            for (int nt = 0; nt < 3; ++nt) {
                const int col = nt * 16 + l;
                term += accn[nt][0] * cinv * bf2f(exem[erow + col])
                        * __expf(trans[col * TT + STOP_IDX]);
            }
        }
        term += __shfl_xor(term, 32); term += __shfl_xor(term, 16); term += __shfl_xor(term, 8);
        term += __shfl_xor(term, 4);  term += __shfl_xor(term, 2);  term += __shfl_xor(term, 1);

        if (l == 0) {
            const float all_paths = __logf(term) + L;
            const int last = tags[b * SS + len - 1];
            out[b] = all_paths - (goldb[b] + trans[last * TT + STOP_IDX]);
        }
    }
}

// ---------------------------------------------------------------------------
extern "C" void kernel_launch(void* const* d_in, const int* in_sizes, int n_in,
                              void* d_out, int out_size, void* d_ws, size_t ws_size,
                              hipStream_t stream) {
    const float* f       = (const float*)d_in[0];
    const float* w       = (const float*)d_in[1];
    const float* bias    = (const float*)d_in[2];
    const float* trans   = (const float*)d_in[3];
    const int*   lengths = (const int*)d_in[4];
    const int*   tags    = (const int*)d_in[5];
    float*       out     = (float*)d_out;

    // ws: exem | Qs | Ls3 | Ebuf | Wbuf | cnt | goldb
    char* ws = (char*)d_ws;
    unsigned short* exem = (unsigned short*)ws;                  // 1,572,864 B
    unsigned short* Qs   = (unsigned short*)(ws + 1572864);      // 6,291,456 B
    float*          Lsc  = (float*)(ws + 7864320);               // 12,288 B
    uint4*          Ebuf = (uint4*)(ws + 7876608);               // 6,144 B
    uint4*          Wbuf = (uint4*)(ws + 7882752);               // 24,576 B
    unsigned int*   cnt  = (unsigned int*)(ws + 7907328);        // 128 B
    float*          goldb= (float*)(ws + 7907456);               // 128 B

    prep_kernel<<<5, 256, 0, stream>>>(w, trans, Ebuf, Wbuf, cnt, goldb);
    fused_kernel<<<BB * 32, 192, 0, stream>>>(f, bias, trans, lengths, tags,
                                              exem, Qs, Lsc, Ebuf, Wbuf, cnt, goldb, out);
}

// Round 3
// 103.584 us; speedup vs baseline: 1.9979x; 1.9979x over previous
//
#include <hip/hip_runtime.h>
#include <math.h>

#define BB 32
#define SS 512
#define HH 256
#define TT 48
#define START_IDX 46
#define STOP_IDX 47

typedef __attribute__((ext_vector_type(8))) short short8;
typedef __attribute__((ext_vector_type(4))) float floatx4;

__device__ __forceinline__ float rfl(float x) {
    return __int_as_float(__builtin_amdgcn_readfirstlane(__float_as_int(x)));
}
__device__ __forceinline__ unsigned int bf16_rne(float x) {
    const unsigned int u = __float_as_uint(x);
    return (u + 0x7fffu + ((u >> 16) & 1u)) >> 16;
}
__device__ __forceinline__ float bf2f(unsigned short h) {
    return __uint_as_float(((unsigned int)h) << 16);
}

// ---------------------------------------------------------------------------
// K1 (prep): blocks 0..3 build w B-frags (2 k-groups each) -> Wbuf;
//            block 4 builds E=exp(trans) B-frags -> Ebuf and zeroes goldb.
// ---------------------------------------------------------------------------
__global__ __launch_bounds__(256) void prep_kernel(
    const float* __restrict__ w, const float* __restrict__ trans,
    uint4* __restrict__ Ebuf, uint4* __restrict__ Wbuf,
    float* __restrict__ goldb)
{
    __shared__ unsigned short wb[64 * 50];
    const int tid = threadIdx.x, blk = blockIdx.x;

    if (blk == 4) {
        if (tid < 32) goldb[tid] = 0.f;
        if (tid < 64) {
            const int g = tid >> 4, cl = tid & 15;
#pragma unroll
            for (int kc = 0; kc < 2; ++kc)
#pragma unroll
                for (int nt = 0; nt < 3; ++nt) {
                    unsigned int p[4];
#pragma unroll
                    for (int h2 = 0; h2 < 4; ++h2) {
                        const int k = kc * 32 + g * 8 + 2 * h2;
                        const int n = nt * 16 + cl;
                        const float lo = (k     < TT) ? __expf(trans[k * TT + n])       : 0.f;
                        const float hi = (k + 1 < TT) ? __expf(trans[(k + 1) * TT + n]) : 0.f;
                        p[h2] = bf16_rne(lo) | (bf16_rne(hi) << 16);
                    }
                    Ebuf[(kc * 3 + nt) * 64 + tid] = make_uint4(p[0], p[1], p[2], p[3]);
                }
        }
        return;
    }

    // w rows [blk*64, blk*64+64) -> bf16 LDS -> 6 frag-blocks
    const int kt0 = blk * 2;
    const int R0  = kt0 * 32;
    for (int i = tid; i < 768; i += 256) {
        const float4 v = ((const float4*)w)[R0 * 12 + i];
        const int lr = i / 12, c4 = (i - lr * 12) * 4;
        unsigned short* d = &wb[lr * 50 + c4];
        d[0] = (unsigned short)bf16_rne(v.x);
        d[1] = (unsigned short)bf16_rne(v.y);
        d[2] = (unsigned short)bf16_rne(v.z);
        d[3] = (unsigned short)bf16_rne(v.w);
    }
    __syncthreads();
    for (int idx = tid; idx < 384; idx += 256) {
        const int fbl = idx >> 6, l = idx & 63;
        const int ktl = fbl / 3, nt = fbl - ktl * 3;
        const int kb  = ktl * 32 + (l >> 4) * 8;
        const int col = nt * 16 + (l & 15);
        unsigned int p[4];
#pragma unroll
        for (int h2 = 0; h2 < 4; ++h2) {
            const unsigned int lo = wb[(kb + 2 * h2)     * 50 + col];
            const unsigned int hi = wb[(kb + 2 * h2 + 1) * 50 + col];
            p[h2] = lo | (hi << 16);
        }
        Wbuf[((kt0 + ktl) * 3 + nt) * 64 + l] = make_uint4(p[0], p[1], p[2], p[3]);
    }
}

// ---------------------------------------------------------------------------
// K2 (fused emission + chunk scan): per (b,chunk) block of 192 threads.
//   phase A: emission of its 16 rows (MFMA, f direct from global, w-frags
//            from ws) -> ebuf (bf16 exp) + plds (f32 pre-exp).  Block-local.
//   terminal row: the unique chunk containing s=len-1 writes 96B to elast.
//   phase B: f32 gold partial -> atomicAdd(goldb[b])  (off critical path)
//   phase C: 16-step chunk scan -> Qs, Ls3  (round-1/2 proven code)
//   NO device fences — the K3 launch boundary is the sync.
// ---------------------------------------------------------------------------
__global__ __launch_bounds__(192, 3) void fused_scan_kernel(
    const float* __restrict__ f, const float* __restrict__ bias,
    const float* __restrict__ trans, const int* __restrict__ lengths,
    const int* __restrict__ tags,
    unsigned short* __restrict__ Qs, float* __restrict__ Ls3,
    const uint4* __restrict__ Ebuf, const uint4* __restrict__ Wbuf,
    float* __restrict__ goldb, unsigned short* __restrict__ elast)
{
    __shared__ __align__(16) unsigned short ebuf[16 * TT];       // 1536 B
    __shared__ __align__(16) unsigned short abuf[3][17 * 56];    // 5712 B
    __shared__ __align__(16) float plds[16 * 48];                // 3072 B

    const int bc = blockIdx.x, b = bc >> 5, c = bc & 31;
    const int len = lengths[b];
    const int tid = threadIdx.x, wv = tid >> 6, l = tid & 63, g = l >> 4, cl = l & 15;
    const int base16 = c << 4;

    const int nraw = (len - 1) - base16;
    if (nraw < 0) return;                       // block-uniform
    const int nsteps = (nraw > 16) ? 16 : nraw;

    // ---- phase A: emission (wave wv = column tile nt) ----
    {
        const float* frow = f + ((size_t)b * SS + base16 + cl) * HH + g * 8;
        float4 fv[8][2];
#pragma unroll
        for (int kt = 0; kt < 8; ++kt) {
            fv[kt][0] = *(const float4*)(frow + kt * 32);
            fv[kt][1] = *(const float4*)(frow + kt * 32 + 4);
        }
        uint4 wf[8];
#pragma unroll
        for (int kt = 0; kt < 8; ++kt) wf[kt] = Wbuf[(kt * 3 + wv) * 64 + l];

        floatx4 acc = {0.f, 0.f, 0.f, 0.f};
#pragma unroll
        for (int kt = 0; kt < 8; ++kt) {
            const unsigned int a0 = bf16_rne(fv[kt][0].x) | (bf16_rne(fv[kt][0].y) << 16);
            const unsigned int a1 = bf16_rne(fv[kt][0].z) | (bf16_rne(fv[kt][0].w) << 16);
            const unsigned int a2 = bf16_rne(fv[kt][1].x) | (bf16_rne(fv[kt][1].y) << 16);
            const unsigned int a3 = bf16_rne(fv[kt][1].z) | (bf16_rne(fv[kt][1].w) << 16);
            const short8 Af = __builtin_bit_cast(short8, make_uint4(a0, a1, a2, a3));
            acc = __builtin_amdgcn_mfma_f32_16x16x32_bf16(
                Af, __builtin_bit_cast(short8, wf[kt]), acc, 0, 0, 0);
        }
        const float bcol = bias[wv * 16 + cl];
#pragma unroll
        for (int r = 0; r < 4; ++r) {
            const int row = 4 * g + r, col = wv * 16 + cl;
            const float el = acc[r] + bcol;              // f32 log-emission
            plds[row * 48 + col] = el;
            ebuf[row * TT + col] = (unsigned short)bf16_rne(__expf(el));
        }
    }
    __syncthreads();

    // terminal emission row (unique chunk: 0 <= nraw <= 15)
    if (nraw <= 15 && tid < 24)
        ((unsigned int*)(elast + b * TT))[tid] = ((const unsigned int*)&ebuf[nraw * TT])[tid];

    // ---- phase B: f32 gold partial (wave 0) ----
    if (wv == 0) {
        float gp = 0.f;
        if (l < 16) {
            const int s = base16 + l;
            if (s < len) {
                const int tag  = tags[b * SS + s];
                const int from = (s == 0) ? START_IDX : tags[b * SS + s - 1];
                gp = plds[l * 48 + tag] + trans[from * TT + tag];
            }
        }
        gp += __shfl_xor(gp, 8); gp += __shfl_xor(gp, 4);
        gp += __shfl_xor(gp, 2); gp += __shfl_xor(gp, 1);
        if (l == 0) atomicAdd(&goldb[b], gp);
    }

    // ---- phase C: chunk scan (wave wv = rowblock) ----
    if (nsteps > 0) {
        uint4 Bf[2][3];
#pragma unroll
        for (int kc = 0; kc < 2; ++kc)
#pragma unroll
            for (int nt = 0; nt < 3; ++nt)
                Bf[kc][nt] = Ebuf[(kc * 3 + nt) * 64 + l];

        floatx4 acc[3];
#pragma unroll
        for (int nt = 0; nt < 3; ++nt)
#pragma unroll
            for (int r = 0; r < 4; ++r)
                acc[nt][r] = (16 * wv + 4 * g + r == nt * 16 + cl) ? 1.f : 0.f;

        float ev[3];
#pragma unroll
        for (int nt = 0; nt < 3; ++nt) ev[nt] = bf2f(ebuf[nt * 16 + cl]);

        float Lrb = 0.f;
        unsigned short* aw = abuf[wv];

        for (int s = 0; s < nsteps; ++s) {
            float scale = 1.f;
            if (s == 8) {
                const float sig = rfl(acc[0][0]);
                Lrb = __logf(sig);
                scale = __builtin_amdgcn_rcpf(sig);
            }
            const float f0 = ev[0] * scale, f1 = ev[1] * scale, f2 = ev[2] * scale;
#pragma unroll
            for (int r = 0; r < 4; ++r) {
                const int rw = (4 * g + r) * 56;
                aw[rw +      cl] = (unsigned short)bf16_rne(acc[0][r] * f0);
                aw[rw + 16 + cl] = (unsigned short)bf16_rne(acc[1][r] * f1);
                aw[rw + 32 + cl] = (unsigned short)bf16_rne(acc[2][r] * f2);
            }
            if (s + 1 < nsteps) {
#pragma unroll
                for (int nt = 0; nt < 3; ++nt)
                    ev[nt] = bf2f(ebuf[(s + 1) * TT + nt * 16 + cl]);
            }
            uint4 a0 = *(const uint4*)&aw[cl * 56 + g * 8];
            uint4 a1 = *(const uint4*)&aw[cl * 56 + 32 + g * 8];
            if (g >= 2) a1 = make_uint4(0, 0, 0, 0);
            const floatx4 z = {0.f, 0.f, 0.f, 0.f};
#pragma unroll
            for (int nt = 0; nt < 3; ++nt) {
                floatx4 d = __builtin_amdgcn_mfma_f32_16x16x32_bf16(
                    __builtin_bit_cast(short8, a0), __builtin_bit_cast(short8, Bf[0][nt]), z, 0, 0, 0);
                d = __builtin_amdgcn_mfma_f32_16x16x32_bf16(
                    __builtin_bit_cast(short8, a1), __builtin_bit_cast(short8, Bf[1][nt]), d, 0, 0, 0);
                acc[nt] = d;
            }
        }

        unsigned short* qb = Qs + (size_t)bc * (TT * 64);
#pragma unroll
        for (int nt = 0; nt < 3; ++nt) {
            const unsigned int lo = bf16_rne(acc[nt][0]) | (bf16_rne(acc[nt][1]) << 16);
            const unsigned int hi = bf16_rne(acc[nt][2]) | (bf16_rne(acc[nt][3]) << 16);
            *(uint2*)&qb[(nt * 16 + cl) * 64 + 16 * wv + 4 * g] = make_uint2(lo, hi);
        }
        if (l == 0) Ls3[bc * 3 + wv] = Lrb;
    }
}

// ---------------------------------------------------------------------------
// K3 (finalize): 4-wave blocked scan (round-1 proven) — slimmed:
//   no trans staging (only row START / col STOP), no gold loop (goldb),
//   terminal emission from elast.
// ---------------------------------------------------------------------------
__global__ __launch_bounds__(256) void finalize_kernel(
    const float* __restrict__ trans,
    const int*   __restrict__ lengths,
    const int*   __restrict__ tags,
    const unsigned short* __restrict__ Qs,
    const float* __restrict__ Ls3,
    const float* __restrict__ goldb,
    const unsigned short* __restrict__ elast,
    float* __restrict__ out)
{
    __shared__ __align__(16) unsigned short Mlds[4][TT * 72];    // 27648 B
    __shared__ __align__(16) unsigned short aw4[4][TT * 56 + 16];// 21632 B
    __shared__ float Lsl[96], fal[96], Lw[4];
    __shared__ __align__(16) unsigned short vlds[64];

    const int tid = threadIdx.x, b = blockIdx.x;
    const int wv = tid >> 6, l = tid & 63, g = l >> 4, cl = l & 15;

    const int len = lengths[b];
    const int nc = (len - 1 + 15) >> 4;          // 16..32

    if (tid < 96) Lsl[tid] = (tid < nc * 3) ? Ls3[b * 96 + tid] : 0.f;
    __syncthreads();
    if (tid < 96) fal[tid] = __expf(Lsl[tid] - Lsl[(tid / 3) * 3]);
    __syncthreads();

    // ---- per-wave partial matrix product over chunks [c0, c1) ----
    const int K  = (nc + 3) >> 2;
    const int c0 = wv * K;
    const int c1 = (c0 + K < nc) ? (c0 + K) : nc;

    floatx4 M[3][3];
#pragma unroll
    for (int mt = 0; mt < 3; ++mt)
#pragma unroll
        for (int nt = 0; nt < 3; ++nt)
#pragma unroll
            for (int r = 0; r < 4; ++r)
                M[mt][nt][r] = (16 * mt + 4 * g + r == 16 * nt + cl) ? 1.f : 0.f;

    float inv = 1.f, Lacc = 0.f;
    unsigned short* aw = aw4[wv];
    const unsigned short* qbase = Qs + (size_t)(b * 32) * (TT * 64);

    uint4 pB0[3], pB1[3];
    if (c0 < c1) {
#pragma unroll
        for (int nt = 0; nt < 3; ++nt) {
            pB0[nt] = *(const uint4*)&qbase[(size_t)c0 * TT * 64 + (nt * 16 + cl) * 64 + g * 8];
            pB1[nt] = *(const uint4*)&qbase[(size_t)c0 * TT * 64 + (nt * 16 + cl) * 64 + 32 + g * 8];
        }
    }

    for (int c = c0; c < c1; ++c) {
        uint4 B0[3], B1[3];
#pragma unroll
        for (int nt = 0; nt < 3; ++nt) {
            B0[nt] = pB0[nt];
            B1[nt] = pB1[nt];
            if (g >= 2) B1[nt] = make_uint4(0, 0, 0, 0);
        }
        const int cn = (c + 1 < c1) ? c + 1 : c;
#pragma unroll
        for (int nt = 0; nt < 3; ++nt) {
            pB0[nt] = *(const uint4*)&qbase[(size_t)cn * TT * 64 + (nt * 16 + cl) * 64 + g * 8];
            pB1[nt] = *(const uint4*)&qbase[(size_t)cn * TT * 64 + (nt * 16 + cl) * 64 + 32 + g * 8];
        }

        const float f0 = inv * fal[c * 3 + 0];
        const float f1 = inv * fal[c * 3 + 1];
        const float f2 = inv * fal[c * 3 + 2];
        Lacc += Lsl[c * 3];

#pragma unroll
        for (int mt = 0; mt < 3; ++mt)
#pragma unroll
            for (int r = 0; r < 4; ++r) {
                const int rw = (16 * mt + 4 * g + r) * 56;
                aw[rw +      cl] = (unsigned short)bf16_rne(M[mt][0][r] * f0);
                aw[rw + 16 + cl] = (unsigned short)bf16_rne(M[mt][1][r] * f1);
                aw[rw + 32 + cl] = (unsigned short)bf16_rne(M[mt][2][r] * f2);
            }

        uint4 A0[3], A1[3];
#pragma unroll
        for (int mt = 0; mt < 3; ++mt) {
            A0[mt] = *(const uint4*)&aw[(16 * mt + cl) * 56 + g * 8];
            A1[mt] = *(const uint4*)&aw[(16 * mt + cl) * 56 + 32 + g * 8];
            if (g >= 2) A1[mt] = make_uint4(0, 0, 0, 0);
        }

        const floatx4 z = {0.f, 0.f, 0.f, 0.f};
#pragma unroll
        for (int mt = 0; mt < 3; ++mt)
#pragma unroll
            for (int nt = 0; nt < 3; ++nt) {
                floatx4 d = __builtin_amdgcn_mfma_f32_16x16x32_bf16(
                    __builtin_bit_cast(short8, A0[mt]), __builtin_bit_cast(short8, B0[nt]), z, 0, 0, 0);
                d = __builtin_amdgcn_mfma_f32_16x16x32_bf16(
                    __builtin_bit_cast(short8, A1[mt]), __builtin_bit_cast(short8, B1[nt]), d, 0, 0, 0);
                M[mt][nt] = d;
            }
        const float sig = rfl(M[0][0][0]);
        inv = __builtin_amdgcn_rcpf(sig);
        Lacc += __logf(sig);
    }

    // store P_w (col-major, stride 72) + log tally
#pragma unroll
    for (int mt = 0; mt < 3; ++mt)
#pragma unroll
        for (int nt = 0; nt < 3; ++nt) {
            const unsigned int lo = bf16_rne(M[mt][nt][0] * inv) | (bf16_rne(M[mt][nt][1] * inv) << 16);
            const unsigned int hi = bf16_rne(M[mt][nt][2] * inv) | (bf16_rne(M[mt][nt][3] * inv) << 16);
            *(uint2*)&Mlds[wv][(nt * 16 + cl) * 72 + 16 * mt + 4 * g] = make_uint2(lo, hi);
        }
    if (l == 0) Lw[wv] = Lacc;
    __syncthreads();

    // ---- wave 0: v · P_0 · P_1 · P_2 · P_3, then terminal ----
    if (wv == 0) {
        const float vj = (l < TT) ? __expf(trans[START_IDX * TT + l]) : 0.f;
        vlds[l] = (unsigned short)bf16_rne(vj);

        float L = 0.f, cinv = 1.f;
        floatx4 accn[3];

        for (int w = 0; w < 4; ++w) {
            uint4 B0[3], B1[3];
#pragma unroll
            for (int nt = 0; nt < 3; ++nt) {
                B0[nt] = *(const uint4*)&Mlds[w][(nt * 16 + cl) * 72 + g * 8];
                B1[nt] = *(const uint4*)&Mlds[w][(nt * 16 + cl) * 72 + 32 + g * 8];
                if (g >= 2) B1[nt] = make_uint4(0, 0, 0, 0);
            }
            const uint4 A0 = *(const uint4*)&vlds[g * 8];
            const uint4 A1 = *(const uint4*)&vlds[32 + g * 8];

            const floatx4 z = {0.f, 0.f, 0.f, 0.f};
#pragma unroll
            for (int nt = 0; nt < 3; ++nt) {
                floatx4 d = __builtin_amdgcn_mfma_f32_16x16x32_bf16(
                    __builtin_bit_cast(short8, A0), __builtin_bit_cast(short8, B0[nt]), z, 0, 0, 0);
                d = __builtin_amdgcn_mfma_f32_16x16x32_bf16(
                    __builtin_bit_cast(short8, A1), __builtin_bit_cast(short8, B1[nt]), d, 0, 0, 0);
                accn[nt] = d;
            }
            const float sig = rfl(accn[0][0]);
            cinv = __builtin_amdgcn_rcpf(sig);
            L += __logf(sig) + Lw[w];
            if (w < 3 && l < 16) {
                vlds[ 0 + l] = (unsigned short)bf16_rne(accn[0][0] * cinv);
                vlds[16 + l] = (unsigned short)bf16_rne(accn[1][0] * cinv);
                vlds[32 + l] = (unsigned short)bf16_rne(accn[2][0] * cinv);
            }
        }

        // terminal: sum_n v[n] * elast[b][n] * exp(trans[n][STOP])
        float term = 0.f;
        if (l < 16) {
#pragma unroll
            for (int nt = 0; nt < 3; ++nt) {
                const int col = nt * 16 + l;
                term += accn[nt][0] * cinv * bf2f(elast[b * TT + col])
                        * __expf(trans[col * TT + STOP_IDX]);
            }
        }
        term += __shfl_xor(term, 32); term += __shfl_xor(term, 16); term += __shfl_xor(term, 8);
        term += __shfl_xor(term, 4);  term += __shfl_xor(term, 2);  term += __shfl_xor(term, 1);

        if (l == 0) {
            const float all_paths = __logf(term) + L;
            const int last = tags[b * SS + len - 1];
            out[b] = all_paths - (goldb[b] + trans[last * TT + STOP_IDX]);
        }
    }
}

// ---------------------------------------------------------------------------
extern "C" void kernel_launch(void* const* d_in, const int* in_sizes, int n_in,
                              void* d_out, int out_size, void* d_ws, size_t ws_size,
                              hipStream_t stream) {
    const float* f       = (const float*)d_in[0];
    const float* w       = (const float*)d_in[1];
    const float* bias    = (const float*)d_in[2];
    const float* trans   = (const float*)d_in[3];
    const int*   lengths = (const int*)d_in[4];
    const int*   tags    = (const int*)d_in[5];
    float*       out     = (float*)d_out;

    // ws: Qs | Ls3 | Ebuf | Wbuf | goldb | elast
    char* ws = (char*)d_ws;
    unsigned short* Qs   = (unsigned short*)ws;                  // 6,291,456 B
    float*          Lsc  = (float*)(ws + 6291456);               // 12,288 B
    uint4*          Ebuf = (uint4*)(ws + 6303744);               // 6,144 B
    uint4*          Wbuf = (uint4*)(ws + 6309888);               // 24,576 B
    float*          goldb= (float*)(ws + 6334464);               // 128 B
    unsigned short* elast= (unsigned short*)(ws + 6334592);      // 3,072 B

    prep_kernel<<<5, 256, 0, stream>>>(w, trans, Ebuf, Wbuf, goldb);
    fused_scan_kernel<<<BB * 32, 192, 0, stream>>>(f, bias, trans, lengths, tags,
                                                   Qs, Lsc, Ebuf, Wbuf, goldb, elast);
    finalize_kernel<<<BB, 256, 0, stream>>>(trans, lengths, tags, Qs, Lsc, goldb, elast, out);
}

// Round 4
// 99.374 us; speedup vs baseline: 2.0826x; 1.0424x over previous
//
#include <hip/hip_runtime.h>
#include <math.h>

#define BB 32
#define SS 512
#define HH 256
#define TT 48
#define START_IDX 46
#define STOP_IDX 47

typedef __attribute__((ext_vector_type(8))) short short8;
typedef __attribute__((ext_vector_type(4))) float floatx4;

__device__ __forceinline__ float rfl(float x) {
    return __int_as_float(__builtin_amdgcn_readfirstlane(__float_as_int(x)));
}
__device__ __forceinline__ unsigned int bf16_rne(float x) {
    const unsigned int u = __float_as_uint(x);
    return (u + 0x7fffu + ((u >> 16) & 1u)) >> 16;
}
__device__ __forceinline__ float bf2f(unsigned short h) {
    return __uint_as_float(((unsigned int)h) << 16);
}

// ---------------------------------------------------------------------------
// K2 (fused emission + chunk scan), now self-contained (no prep kernel):
//   - per-block w-frag build from global w (L1/L2-resident, 48 KB)
//   - cooperative E=exp(trans) frag build in LDS (wave wv -> frags wv, wv+3)
//   - emission 16 rows via MFMA -> ebuf (bf16 exp) + plds (f32 pre-exp)
//   - gold partial -> goldp[bc] (unconditional slot write, no atomics/zeroing)
//   - scan with init-skip: acc starts at P_1 (identity step folded analytically)
//   terminal row -> elast; Q product -> Qs; rowblock logscale -> Ls3.
// ---------------------------------------------------------------------------
__global__ __launch_bounds__(192, 3) void fused_scan_kernel(
    const float* __restrict__ f, const float* __restrict__ w,
    const float* __restrict__ bias, const float* __restrict__ trans,
    const int* __restrict__ lengths, const int* __restrict__ tags,
    unsigned short* __restrict__ Qs, float* __restrict__ Ls3,
    float* __restrict__ goldp, unsigned short* __restrict__ elast)
{
    __shared__ __align__(16) unsigned short ebuf[16 * TT];       // 1536 B
    __shared__ __align__(16) unsigned short abuf[3][17 * 56];    // 5712 B
    __shared__ __align__(16) float plds[16 * 48];                // 3072 B
    __shared__ __align__(16) uint4 efr[6 * 64];                  // 6144 B

    const int bc = blockIdx.x, b = bc >> 5, c = bc & 31;
    const int len = lengths[b];
    const int tid = threadIdx.x, wv = tid >> 6, l = tid & 63, g = l >> 4, cl = l & 15;
    const int base16 = c << 4;

    const int nraw = (len - 1) - base16;
    if (nraw < 0) {                              // block-uniform
        if (tid == 0) goldp[bc] = 0.f;           // poison-safe slot
        return;
    }
    const int nsteps = (nraw > 16) ? 16 : nraw;

    // ---- cooperative E-frag build (only needed for scan steps >= 1) ----
    if (nsteps > 1) {
#pragma unroll
        for (int kc = 0; kc < 2; ++kc) {         // wave wv builds frag (kc, nt=wv)
            unsigned int p[4];
#pragma unroll
            for (int h2 = 0; h2 < 4; ++h2) {
                const int k = kc * 32 + g * 8 + 2 * h2;
                const int n = wv * 16 + cl;
                const float lo = (k     < TT) ? __expf(trans[k * TT + n])       : 0.f;
                const float hi = (k + 1 < TT) ? __expf(trans[(k + 1) * TT + n]) : 0.f;
                p[h2] = bf16_rne(lo) | (bf16_rne(hi) << 16);
            }
            efr[(kc * 3 + wv) * 64 + l] = make_uint4(p[0], p[1], p[2], p[3]);
        }
    }

    // ---- phase A: emission (wave wv = column tile nt) ----
    {
        // per-block w B-frags (same layout as old prep kernel)
        const int wcol = wv * 16 + cl;
        uint4 wf[8];
#pragma unroll
        for (int kt = 0; kt < 8; ++kt) {
            unsigned int p[4];
#pragma unroll
            for (int h2 = 0; h2 < 4; ++h2) {
                const int k = kt * 32 + g * 8 + 2 * h2;
                p[h2] = bf16_rne(w[k * TT + wcol])
                      | (bf16_rne(w[(k + 1) * TT + wcol]) << 16);
            }
            wf[kt] = make_uint4(p[0], p[1], p[2], p[3]);
        }

        const float* frow = f + ((size_t)b * SS + base16 + cl) * HH + g * 8;
        floatx4 acc = {0.f, 0.f, 0.f, 0.f};
#pragma unroll
        for (int kt = 0; kt < 8; ++kt) {
            const float4 v0 = *(const float4*)(frow + kt * 32);
            const float4 v1 = *(const float4*)(frow + kt * 32 + 4);
            const unsigned int a0 = bf16_rne(v0.x) | (bf16_rne(v0.y) << 16);
            const unsigned int a1 = bf16_rne(v0.z) | (bf16_rne(v0.w) << 16);
            const unsigned int a2 = bf16_rne(v1.x) | (bf16_rne(v1.y) << 16);
            const unsigned int a3 = bf16_rne(v1.z) | (bf16_rne(v1.w) << 16);
            const short8 Af = __builtin_bit_cast(short8, make_uint4(a0, a1, a2, a3));
            acc = __builtin_amdgcn_mfma_f32_16x16x32_bf16(
                Af, __builtin_bit_cast(short8, wf[kt]), acc, 0, 0, 0);
        }
        const float bcol = bias[wv * 16 + cl];
#pragma unroll
        for (int r = 0; r < 4; ++r) {
            const int row = 4 * g + r, col = wv * 16 + cl;
            const float el = acc[r] + bcol;              // f32 log-emission
            plds[row * 48 + col] = el;
            ebuf[row * TT + col] = (unsigned short)bf16_rne(__expf(el));
        }
    }
    __syncthreads();

    // terminal emission row (unique chunk: 0 <= nraw <= 15)
    if (nraw <= 15 && tid < 24)
        ((unsigned int*)(elast + b * TT))[tid] = ((const unsigned int*)&ebuf[nraw * TT])[tid];

    // ---- phase B: f32 gold partial (wave 0) -> goldp[bc] ----
    if (wv == 0) {
        float gp = 0.f;
        if (l < 16) {
            const int s = base16 + l;
            if (s < len) {
                const int tag  = tags[b * SS + s];
                const int from = (s == 0) ? START_IDX : tags[b * SS + s - 1];
                gp = plds[l * 48 + tag] + trans[from * TT + tag];
            }
        }
        gp += __shfl_xor(gp, 8); gp += __shfl_xor(gp, 4);
        gp += __shfl_xor(gp, 2); gp += __shfl_xor(gp, 1);
        if (l == 0) goldp[bc] = gp;
    }

    // ---- phase C: chunk scan (wave wv = rowblock), init-skip ----
    if (nsteps > 0) {
        // acc = P_1[row][col] = e0[row] * E[row][col]   (identity step folded)
        floatx4 acc[3];
#pragma unroll
        for (int r = 0; r < 4; ++r) {
            const int row = 16 * wv + 4 * g + r;
            const float e0 = bf2f(ebuf[row]);            // step-0 emission at 'row'
#pragma unroll
            for (int nt = 0; nt < 3; ++nt)
                acc[nt][r] = e0 * __expf(trans[row * TT + nt * 16 + cl]);
        }

        float ev[3];
        uint4 Bf[2][3];
        if (nsteps > 1) {
#pragma unroll
            for (int nt = 0; nt < 3; ++nt) ev[nt] = bf2f(ebuf[1 * TT + nt * 16 + cl]);
#pragma unroll
            for (int kc = 0; kc < 2; ++kc)
#pragma unroll
                for (int nt = 0; nt < 3; ++nt)
                    Bf[kc][nt] = efr[(kc * 3 + nt) * 64 + l];
        }

        float Lrb = 0.f;
        unsigned short* aw = abuf[wv];

        for (int s = 1; s < nsteps; ++s) {
            float scale = 1.f;
            if (s == 8) {   // sigma from post-step-7 acc; applied exactly once
                const float sig = rfl(acc[0][0]);
                Lrb = __logf(sig);
                scale = __builtin_amdgcn_rcpf(sig);
            }
            const float f0 = ev[0] * scale, f1 = ev[1] * scale, f2 = ev[2] * scale;
#pragma unroll
            for (int r = 0; r < 4; ++r) {
                const int rw = (4 * g + r) * 56;
                aw[rw +      cl] = (unsigned short)bf16_rne(acc[0][r] * f0);
                aw[rw + 16 + cl] = (unsigned short)bf16_rne(acc[1][r] * f1);
                aw[rw + 32 + cl] = (unsigned short)bf16_rne(acc[2][r] * f2);
            }
            if (s + 1 < nsteps) {   // off-chain emission prefetch
#pragma unroll
                for (int nt = 0; nt < 3; ++nt)
                    ev[nt] = bf2f(ebuf[(s + 1) * TT + nt * 16 + cl]);
            }
            uint4 a0 = *(const uint4*)&aw[cl * 56 + g * 8];
            uint4 a1 = *(const uint4*)&aw[cl * 56 + 32 + g * 8];
            if (g >= 2) a1 = make_uint4(0, 0, 0, 0);   // k >= 48 pad
            const floatx4 z = {0.f, 0.f, 0.f, 0.f};
#pragma unroll
            for (int nt = 0; nt < 3; ++nt) {
                floatx4 d = __builtin_amdgcn_mfma_f32_16x16x32_bf16(
                    __builtin_bit_cast(short8, a0), __builtin_bit_cast(short8, Bf[0][nt]), z, 0, 0, 0);
                d = __builtin_amdgcn_mfma_f32_16x16x32_bf16(
                    __builtin_bit_cast(short8, a1), __builtin_bit_cast(short8, Bf[1][nt]), d, 0, 0, 0);
                acc[nt] = d;
            }
        }

        unsigned short* qb = Qs + (size_t)bc * (TT * 64);
#pragma unroll
        for (int nt = 0; nt < 3; ++nt) {
            const unsigned int lo = bf16_rne(acc[nt][0]) | (bf16_rne(acc[nt][1]) << 16);
            const unsigned int hi = bf16_rne(acc[nt][2]) | (bf16_rne(acc[nt][3]) << 16);
            *(uint2*)&qb[(nt * 16 + cl) * 64 + 16 * wv + 4 * g] = make_uint2(lo, hi);
        }
        if (l == 0) Ls3[bc * 3 + wv] = Lrb;
    }
}

// ---------------------------------------------------------------------------
// K3 (finalize): 4-wave blocked scan with init-skip (M starts at fal*Q_c0),
//   gold summed from per-chunk slots by wave 1, combine by wave 0.
// ---------------------------------------------------------------------------
__global__ __launch_bounds__(256) void finalize_kernel(
    const float* __restrict__ trans,
    const int*   __restrict__ lengths,
    const int*   __restrict__ tags,
    const unsigned short* __restrict__ Qs,
    const float* __restrict__ Ls3,
    const float* __restrict__ goldp,
    const unsigned short* __restrict__ elast,
    float* __restrict__ out)
{
    __shared__ __align__(16) unsigned short Mlds[4][TT * 72];    // 27648 B
    __shared__ __align__(16) unsigned short aw4[4][TT * 56 + 16];// 21632 B
    __shared__ float Lsl[96], fal[96], Lw[4];
    __shared__ __align__(16) unsigned short vlds[64];
    __shared__ float goldtot;

    const int tid = threadIdx.x, b = blockIdx.x;
    const int wv = tid >> 6, l = tid & 63, g = l >> 4, cl = l & 15;

    const int len = lengths[b];
    const int nc = (len - 1 + 15) >> 4;          // 16..32

    if (tid < 96) Lsl[tid] = (tid < nc * 3) ? Ls3[b * 96 + tid] : 0.f;
    __syncthreads();
    if (tid < 96) fal[tid] = __expf(Lsl[tid] - Lsl[(tid / 3) * 3]);
    __syncthreads();

    // gold total (wave 1, off the matrix critical path)
    if (wv == 1) {
        float gsum = (l < 32) ? goldp[b * 32 + l] : 0.f;
        gsum += __shfl_xor(gsum, 16); gsum += __shfl_xor(gsum, 8);
        gsum += __shfl_xor(gsum, 4);  gsum += __shfl_xor(gsum, 2);
        gsum += __shfl_xor(gsum, 1);
        if (l == 0) goldtot = gsum;
    }

    // ---- per-wave partial matrix product over chunks [c0, c1) ----
    const int K  = (nc + 3) >> 2;
    const int c0 = wv * K;
    const int c1 = (c0 + K < nc) ? (c0 + K) : nc;
    const unsigned short* qbase = Qs + (size_t)(b * 32) * (TT * 64);

    // init-skip: M = fal-rowscaled Q_c0 read in C-layout
    floatx4 M[3][3];
    {
        const unsigned short* qb0 = qbase + (size_t)c0 * TT * 64;
        const float fm0 = fal[c0 * 3 + 0], fm1 = fal[c0 * 3 + 1], fm2 = fal[c0 * 3 + 2];
        const float fm[3] = {fm0, fm1, fm2};
#pragma unroll
        for (int mt = 0; mt < 3; ++mt)
#pragma unroll
            for (int nt = 0; nt < 3; ++nt) {
                const uint2 q = *(const uint2*)&qb0[(nt * 16 + cl) * 64 + 16 * mt + 4 * g];
                M[mt][nt][0] = bf2f((unsigned short)(q.x & 0xffffu)) * fm[mt];
                M[mt][nt][1] = bf2f((unsigned short)(q.x >> 16))     * fm[mt];
                M[mt][nt][2] = bf2f((unsigned short)(q.y & 0xffffu)) * fm[mt];
                M[mt][nt][3] = bf2f((unsigned short)(q.y >> 16))     * fm[mt];
            }
    }
    float Lacc = Lsl[c0 * 3];
    const float sig0 = rfl(M[0][0][0]);          // > 0 always
    float inv = __builtin_amdgcn_rcpf(sig0);
    Lacc += __logf(sig0);

    unsigned short* aw = aw4[wv];

    uint4 pB0[3], pB1[3];
    if (c0 + 1 < c1) {
#pragma unroll
        for (int nt = 0; nt < 3; ++nt) {
            pB0[nt] = *(const uint4*)&qbase[(size_t)(c0 + 1) * TT * 64 + (nt * 16 + cl) * 64 + g * 8];
            pB1[nt] = *(const uint4*)&qbase[(size_t)(c0 + 1) * TT * 64 + (nt * 16 + cl) * 64 + 32 + g * 8];
        }
    }

    for (int c = c0 + 1; c < c1; ++c) {
        uint4 B0[3], B1[3];
#pragma unroll
        for (int nt = 0; nt < 3; ++nt) {
            B0[nt] = pB0[nt];
            B1[nt] = pB1[nt];
            if (g >= 2) B1[nt] = make_uint4(0, 0, 0, 0);
        }
        const int cn = (c + 1 < c1) ? c + 1 : c;
#pragma unroll
        for (int nt = 0; nt < 3; ++nt) {
            pB0[nt] = *(const uint4*)&qbase[(size_t)cn * TT * 64 + (nt * 16 + cl) * 64 + g * 8];
            pB1[nt] = *(const uint4*)&qbase[(size_t)cn * TT * 64 + (nt * 16 + cl) * 64 + 32 + g * 8];
        }

        const float f0 = inv * fal[c * 3 + 0];
        const float f1 = inv * fal[c * 3 + 1];
        const float f2 = inv * fal[c * 3 + 2];
        Lacc += Lsl[c * 3];

#pragma unroll
        for (int mt = 0; mt < 3; ++mt)
#pragma unroll
            for (int r = 0; r < 4; ++r) {
                const int rw = (16 * mt + 4 * g + r) * 56;
                aw[rw +      cl] = (unsigned short)bf16_rne(M[mt][0][r] * f0);
                aw[rw + 16 + cl] = (unsigned short)bf16_rne(M[mt][1][r] * f1);
                aw[rw + 32 + cl] = (unsigned short)bf16_rne(M[mt][2][r] * f2);
            }

        uint4 A0[3], A1[3];
#pragma unroll
        for (int mt = 0; mt < 3; ++mt) {
            A0[mt] = *(const uint4*)&aw[(16 * mt + cl) * 56 + g * 8];
            A1[mt] = *(const uint4*)&aw[(16 * mt + cl) * 56 + 32 + g * 8];
            if (g >= 2) A1[mt] = make_uint4(0, 0, 0, 0);
        }

        const floatx4 z = {0.f, 0.f, 0.f, 0.f};
#pragma unroll
        for (int mt = 0; mt < 3; ++mt)
#pragma unroll
            for (int nt = 0; nt < 3; ++nt) {
                floatx4 d = __builtin_amdgcn_mfma_f32_16x16x32_bf16(
                    __builtin_bit_cast(short8, A0[mt]), __builtin_bit_cast(short8, B0[nt]), z, 0, 0, 0);
                d = __builtin_amdgcn_mfma_f32_16x16x32_bf16(
                    __builtin_bit_cast(short8, A1[mt]), __builtin_bit_cast(short8, B1[nt]), d, 0, 0, 0);
                M[mt][nt] = d;
            }
        const float sig = rfl(M[0][0][0]);
        inv = __builtin_amdgcn_rcpf(sig);
        Lacc += __logf(sig);
    }

    // store P_w (col-major, stride 72) + log tally
#pragma unroll
    for (int mt = 0; mt < 3; ++mt)
#pragma unroll
        for (int nt = 0; nt < 3; ++nt) {
            const unsigned int lo = bf16_rne(M[mt][nt][0] * inv) | (bf16_rne(M[mt][nt][1] * inv) << 16);
            const unsigned int hi = bf16_rne(M[mt][nt][2] * inv) | (bf16_rne(M[mt][nt][3] * inv) << 16);
            *(uint2*)&Mlds[wv][(nt * 16 + cl) * 72 + 16 * mt + 4 * g] = make_uint2(lo, hi);
        }
    if (l == 0) Lw[wv] = Lacc;
    __syncthreads();

    // ---- wave 0: v · P_0 · P_1 · P_2 · P_3, then terminal ----
    if (wv == 0) {
        const float vj = (l < TT) ? __expf(trans[START_IDX * TT + l]) : 0.f;
        vlds[l] = (unsigned short)bf16_rne(vj);

        float L = 0.f, cinv = 1.f;
        floatx4 accn[3];

        for (int w2 = 0; w2 < 4; ++w2) {
            uint4 B0[3], B1[3];
#pragma unroll
            for (int nt = 0; nt < 3; ++nt) {
                B0[nt] = *(const uint4*)&Mlds[w2][(nt * 16 + cl) * 72 + g * 8];
                B1[nt] = *(const uint4*)&Mlds[w2][(nt * 16 + cl) * 72 + 32 + g * 8];
                if (g >= 2) B1[nt] = make_uint4(0, 0, 0, 0);
            }
            const uint4 A0 = *(const uint4*)&vlds[g * 8];
            const uint4 A1 = *(const uint4*)&vlds[32 + g * 8];

            const floatx4 z = {0.f, 0.f, 0.f, 0.f};
#pragma unroll
            for (int nt = 0; nt < 3; ++nt) {
                floatx4 d = __builtin_amdgcn_mfma_f32_16x16x32_bf16(
                    __builtin_bit_cast(short8, A0), __builtin_bit_cast(short8, B0[nt]), z, 0, 0, 0);
                d = __builtin_amdgcn_mfma_f32_16x16x32_bf16(
                    __builtin_bit_cast(short8, A1), __builtin_bit_cast(short8, B1[nt]), d, 0, 0, 0);
                accn[nt] = d;
            }
            const float sig = rfl(accn[0][0]);
            cinv = __builtin_amdgcn_rcpf(sig);
            L += __logf(sig) + Lw[w2];
            if (w2 < 3 && l < 16) {
                vlds[ 0 + l] = (unsigned short)bf16_rne(accn[0][0] * cinv);
                vlds[16 + l] = (unsigned short)bf16_rne(accn[1][0] * cinv);
                vlds[32 + l] = (unsigned short)bf16_rne(accn[2][0] * cinv);
            }
        }

        // terminal: sum_n v[n] * elast[b][n] * exp(trans[n][STOP])
        float term = 0.f;
        if (l < 16) {
#pragma unroll
            for (int nt = 0; nt < 3; ++nt) {
                const int col = nt * 16 + l;
                term += accn[nt][0] * cinv * bf2f(elast[b * TT + col])
                        * __expf(trans[col * TT + STOP_IDX]);
            }
        }
        term += __shfl_xor(term, 32); term += __shfl_xor(term, 16); term += __shfl_xor(term, 8);
        term += __shfl_xor(term, 4);  term += __shfl_xor(term, 2);  term += __shfl_xor(term, 1);

        if (l == 0) {
            const float all_paths = __logf(term) + L;
            const int last = tags[b * SS + len - 1];
            out[b] = all_paths - (goldtot + trans[last * TT + STOP_IDX]);
        }
    }
}

// ---------------------------------------------------------------------------
extern "C" void kernel_launch(void* const* d_in, const int* in_sizes, int n_in,
                              void* d_out, int out_size, void* d_ws, size_t ws_size,
                              hipStream_t stream) {
    const float* f       = (const float*)d_in[0];
    const float* w       = (const float*)d_in[1];
    const float* bias    = (const float*)d_in[2];
    const float* trans   = (const float*)d_in[3];
    const int*   lengths = (const int*)d_in[4];
    const int*   tags    = (const int*)d_in[5];
    float*       out     = (float*)d_out;

    // ws: Qs | Ls3 | goldp | elast
    char* ws = (char*)d_ws;
    unsigned short* Qs   = (unsigned short*)ws;                  // 6,291,456 B
    float*          Lsc  = (float*)(ws + 6291456);               // 12,288 B
    float*          goldp= (float*)(ws + 6303744);               // 4,096 B
    unsigned short* elast= (unsigned short*)(ws + 6307840);      // 3,072 B

    fused_scan_kernel<<<BB * 32, 192, 0, stream>>>(f, w, bias, trans, lengths, tags,
                                                   Qs, Lsc, goldp, elast);
    finalize_kernel<<<BB, 256, 0, stream>>>(trans, lengths, tags, Qs, Lsc, goldp, elast, out);
}